// Round 1
// baseline (2987.921 us; speedup 1.0000x reference)
//
#include <hip/hip_runtime.h>
#include <hip/hip_bf16.h>

#define T_TOK   4096
#define DMODEL  2048
#define FFN     5632
#define NE      8
#define NTILES_MAX 136
#define NROWS_MAX  (NTILES_MAX*64)

// meta layout (indices into (int*)d_ws)
#define M_CNT     0      // 8 ints
#define M_OFFS    8      // 9 ints
#define M_CUR     17     // 8 ints
#define M_TILE_E  32     // 136 ints
#define M_ROW_TOK 256    // 8704 ints
#define M_ROW_W   8960   // 8704 floats
#define M_TK_E    17664  // 4096 ints (e0 | e1<<16)
#define M_TK_W0   21760  // 4096 floats
#define M_TK_W1   25856  // 4096 floats
#define HBUF_OFF  (1<<20)

typedef __bf16 bf16x8 __attribute__((ext_vector_type(8)));
typedef float  f32x4  __attribute__((ext_vector_type(4)));

__device__ inline void pack4_bf16(__hip_bfloat16* dst, float a, float b, float c, float d){
  union { __hip_bfloat16 h[4]; unsigned long long u; } q;
  q.h[0] = __float2bfloat16(a);
  q.h[1] = __float2bfloat16(b);
  q.h[2] = __float2bfloat16(c);
  q.h[3] = __float2bfloat16(d);
  *(unsigned long long*)dst = q.u;
}

// ---------------- init: out = bias broadcast; zero counters ----------------
__global__ __launch_bounds__(256) void k_init(float* __restrict__ out,
                                              const float* __restrict__ bias,
                                              int* __restrict__ meta){
  int idx = blockIdx.x * 256 + threadIdx.x;
  if (idx < 32) meta[idx] = 0;                 // cnt, offs, cur
  const float4* b4 = (const float4*)bias;
  int total4 = T_TOK * DMODEL / 4;
  if (idx < total4)
    ((float4*)out)[idx] = b4[idx & (DMODEL/4 - 1)];
}

// ---------------- router: fp32 logits, top-2, softmax, counts ----------------
__global__ __launch_bounds__(256) void k_router(const float* __restrict__ x,
                                                const float* __restrict__ gw,
                                                int* __restrict__ meta){
  int wid = threadIdx.x >> 6, lane = threadIdx.x & 63;
  int t = blockIdx.x * 4 + wid;
  float acc[NE];
  #pragma unroll
  for (int e = 0; e < NE; e++) acc[e] = 0.f;
  const float* xr = x + (size_t)t * DMODEL;
  for (int k = lane; k < DMODEL; k += 64){
    float xv = xr[k];
    #pragma unroll
    for (int e = 0; e < NE; e++) acc[e] += xv * gw[e * DMODEL + k];
  }
  #pragma unroll
  for (int e = 0; e < NE; e++){
    #pragma unroll
    for (int off = 32; off > 0; off >>= 1)
      acc[e] += __shfl_xor(acc[e], off, 64);
  }
  if (lane == 0){
    int e0 = 0; float v0 = acc[0];
    #pragma unroll
    for (int e = 1; e < NE; e++) if (acc[e] > v0){ v0 = acc[e]; e0 = e; }
    int e1 = -1; float v1 = -3.4e38f;
    #pragma unroll
    for (int e = 0; e < NE; e++) if (e != e0 && acc[e] > v1){ v1 = acc[e]; e1 = e; }
    float w0 = 1.f / (1.f + __expf(v1 - v0));   // softmax over [v0, v1]
    meta[M_TK_E + t] = e0 | (e1 << 16);
    ((float*)meta)[M_TK_W0 + t] = w0;
    ((float*)meta)[M_TK_W1 + t] = 1.f - w0;
    atomicAdd(&meta[M_CNT + e0], 1);
    atomicAdd(&meta[M_CNT + e1], 1);
  }
}

// ------------- offsets: pad counts to 64, prefix sum, tile->expert map -------------
__global__ __launch_bounds__(256) void k_offsets(int* __restrict__ meta){
  __shared__ int soffs[NE + 1];
  int tid = threadIdx.x;
  if (tid == 0){
    int off = 0;
    for (int e = 0; e < NE; e++){
      soffs[e] = off;
      meta[M_OFFS + e] = off;
      off += (meta[M_CNT + e] + 63) & ~63;
    }
    soffs[NE] = off;
    meta[M_OFFS + NE] = off;
  }
  __syncthreads();
  for (int i = tid; i < NTILES_MAX; i += 256){
    int r = i * 64, te = -1;
    for (int j = 0; j < NE; j++)
      if (r >= soffs[j] && r < soffs[j + 1]) te = j;
    meta[M_TILE_E + i] = te;
  }
  for (int r = tid; r < NROWS_MAX; r += 256){
    meta[M_ROW_TOK + r] = -1;
    ((float*)meta)[M_ROW_W + r] = 0.f;
  }
}

// ------------- scatter tokens into compacted per-expert row lists -------------
__global__ __launch_bounds__(256) void k_scatter(int* __restrict__ meta){
  int t = blockIdx.x * 256 + threadIdx.x;
  if (t >= T_TOK) return;
  int pk = meta[M_TK_E + t];
  int e0 = pk & 0xffff, e1 = pk >> 16;
  float w0 = ((float*)meta)[M_TK_W0 + t];
  float w1 = ((float*)meta)[M_TK_W1 + t];
  int p0 = atomicAdd(&meta[M_CUR + e0], 1);
  int r0 = meta[M_OFFS + e0] + p0;
  meta[M_ROW_TOK + r0] = t;
  ((float*)meta)[M_ROW_W + r0] = w0;
  int p1 = atomicAdd(&meta[M_CUR + e1], 1);
  int r1 = meta[M_OFFS + e1] + p1;
  meta[M_ROW_TOK + r1] = t;
  ((float*)meta)[M_ROW_W + r1] = w1;
}

// ------------- pass 2: h = silu(x W_g^T) * (x W_u^T), gathered rows -------------
__global__ __launch_bounds__(256) void k_ffn_in(const float* __restrict__ x,
                                                const float* __restrict__ wg_all,
                                                const float* __restrict__ wu_all,
                                                const int* __restrict__ meta,
                                                __hip_bfloat16* __restrict__ hbuf){
  int e = meta[M_TILE_E + blockIdx.y];
  if (e < 0) return;
  const int r0 = blockIdx.y * 64;
  const int n0 = blockIdx.x * 64;
  const int tid = threadIdx.x;
  const int wid = tid >> 6, lane = tid & 63, l15 = lane & 15, quad = lane >> 4;

  __shared__ int toks[64];
  __shared__ __align__(16) __hip_bfloat16 As[64][40];
  __shared__ __align__(16) __hip_bfloat16 Bg[64][40];
  __shared__ __align__(16) __hip_bfloat16 Bu[64][40];

  if (tid < 64) toks[tid] = meta[M_ROW_TOK + r0 + tid];
  __syncthreads();

  const float* wg = wg_all + (size_t)e * FFN * DMODEL + (size_t)n0 * DMODEL;
  const float* wu = wu_all + (size_t)e * FFN * DMODEL + (size_t)n0 * DMODEL;

  f32x4 zero = {0.f, 0.f, 0.f, 0.f};
  f32x4 ag[4] = {zero, zero, zero, zero};
  f32x4 au[4] = {zero, zero, zero, zero};

  for (int k0 = 0; k0 < DMODEL; k0 += 32){
    for (int i = tid; i < 512; i += 256){
      int row = i >> 3, c = (i & 7) * 4;
      int tok = toks[row];
      float4 v = make_float4(0.f, 0.f, 0.f, 0.f);
      if (tok >= 0) v = *(const float4*)&x[(size_t)tok * DMODEL + k0 + c];
      pack4_bf16(&As[row][c], v.x, v.y, v.z, v.w);
      float4 g = *(const float4*)&wg[(size_t)row * DMODEL + k0 + c];
      pack4_bf16(&Bg[row][c], g.x, g.y, g.z, g.w);
      float4 u = *(const float4*)&wu[(size_t)row * DMODEL + k0 + c];
      pack4_bf16(&Bu[row][c], u.x, u.y, u.z, u.w);
    }
    __syncthreads();
    bf16x8 af = *(const bf16x8*)&As[16 * wid + l15][quad * 8];
    #pragma unroll
    for (int nt = 0; nt < 4; nt++){
      bf16x8 bg = *(const bf16x8*)&Bg[nt * 16 + l15][quad * 8];
      ag[nt] = __builtin_amdgcn_mfma_f32_16x16x32_bf16(af, bg, ag[nt], 0, 0, 0);
    }
    #pragma unroll
    for (int nt = 0; nt < 4; nt++){
      bf16x8 bu = *(const bf16x8*)&Bu[nt * 16 + l15][quad * 8];
      au[nt] = __builtin_amdgcn_mfma_f32_16x16x32_bf16(af, bu, au[nt], 0, 0, 0);
    }
    __syncthreads();
  }

  #pragma unroll
  for (int nt = 0; nt < 4; nt++){
    #pragma unroll
    for (int reg = 0; reg < 4; reg++){
      float g = ag[nt][reg], u = au[nt][reg];
      float h = g / (1.f + __expf(-g)) * u;     // silu(g) * u
      int r = r0 + 16 * wid + quad * 4 + reg;
      hbuf[(size_t)r * FFN + n0 + nt * 16 + l15] = __float2bfloat16(h);
    }
  }
}

// ------------- pass 3: y = h W_o^T, scatter-add weight*y into out -------------
__global__ __launch_bounds__(256) void k_ffn_out(const __hip_bfloat16* __restrict__ hbuf,
                                                 const float* __restrict__ wo_all,
                                                 const int* __restrict__ meta,
                                                 float* __restrict__ out){
  int e = meta[M_TILE_E + blockIdx.y];
  if (e < 0) return;
  const int r0 = blockIdx.y * 64;
  const int n0 = blockIdx.x * 64;
  const int tid = threadIdx.x;
  const int wid = tid >> 6, lane = tid & 63, l15 = lane & 15, quad = lane >> 4;

  __shared__ __align__(16) __hip_bfloat16 As[64][40];
  __shared__ __align__(16) __hip_bfloat16 Bs[64][40];

  const float* wo = wo_all + (size_t)e * DMODEL * FFN + (size_t)n0 * FFN;
  const float* row_w = (const float*)meta + M_ROW_W;

  f32x4 zero = {0.f, 0.f, 0.f, 0.f};
  f32x4 acc[4] = {zero, zero, zero, zero};

  const int arow = tid >> 2;          // 0..63
  const int ac   = (tid & 3) * 8;     // bf16 elems: 0,8,16,24

  for (int k0 = 0; k0 < FFN; k0 += 32){
    *(uint4*)&As[arow][ac] = *(const uint4*)&hbuf[(size_t)(r0 + arow) * FFN + k0 + ac];
    for (int i = tid; i < 512; i += 256){
      int row = i >> 3, c = (i & 7) * 4;
      float4 v = *(const float4*)&wo[(size_t)row * FFN + k0 + c];
      pack4_bf16(&Bs[row][c], v.x, v.y, v.z, v.w);
    }
    __syncthreads();
    bf16x8 af = *(const bf16x8*)&As[16 * wid + l15][quad * 8];
    #pragma unroll
    for (int nt = 0; nt < 4; nt++){
      bf16x8 bf = *(const bf16x8*)&Bs[nt * 16 + l15][quad * 8];
      acc[nt] = __builtin_amdgcn_mfma_f32_16x16x32_bf16(af, bf, acc[nt], 0, 0, 0);
    }
    __syncthreads();
  }

  #pragma unroll
  for (int reg = 0; reg < 4; reg++){
    int r = r0 + 16 * wid + quad * 4 + reg;
    int tok = meta[M_ROW_TOK + r];
    if (tok < 0) continue;
    float wgt = row_w[r];
    #pragma unroll
    for (int nt = 0; nt < 4; nt++){
      atomicAdd(&out[(size_t)tok * DMODEL + n0 + nt * 16 + l15], wgt * acc[nt][reg]);
    }
  }
}

extern "C" void kernel_launch(void* const* d_in, const int* in_sizes, int n_in,
                              void* d_out, int out_size, void* d_ws, size_t ws_size,
                              hipStream_t stream){
  const float* x    = (const float*)d_in[0];
  const float* gw   = (const float*)d_in[1];
  const float* wg   = (const float*)d_in[2];
  const float* wu   = (const float*)d_in[3];
  const float* wo   = (const float*)d_in[4];
  const float* bias = (const float*)d_in[5];
  float* out = (float*)d_out;
  int* meta = (int*)d_ws;
  __hip_bfloat16* hbuf = (__hip_bfloat16*)((char*)d_ws + HBUF_OFF);

  k_init<<<T_TOK * DMODEL / 4 / 256, 256, 0, stream>>>(out, bias, meta);
  k_router<<<T_TOK / 4, 256, 0, stream>>>(x, gw, meta);
  k_offsets<<<1, 256, 0, stream>>>(meta);
  k_scatter<<<T_TOK / 256, 256, 0, stream>>>(meta);
  k_ffn_in<<<dim3(FFN / 64, NTILES_MAX), 256, 0, stream>>>(x, wg, wu, meta, hbuf);
  k_ffn_out<<<dim3(DMODEL / 64, NTILES_MAX), 256, 0, stream>>>(hbuf, wo, meta, out);
}